// Round 17
// baseline (647.165 us; speedup 1.0000x reference)
//
#include <hip/hip_runtime.h>

// Problem constants
constexpr int N_TOK = 8192;      // B*S
constexpr int D_IN  = 2048;
constexpr int H_OUT = 4096;
constexpr int NEXP  = 8;
constexpr float ENT_W = 0.1f;
constexpr float MAX_USAGE = 0.3f;

// GEMM tiling: 128x128 tile, BK=32, 8 waves (512 thr) of 64x32 wave-tiles.
// acc[4][2]=32 AGPR; frag-offset collapsed to base+immediates -> ~60 unified
// regs -> 8 waves/SIMD legal -> 4 blocks/CU x 8 waves = 32 waves/CU.
// LDS 33 KB x 4 = 135 KB < 160 KB.
constexpr int TM = 128;
constexpr int TH = 128;
constexpr int BK = 32;                // K-step (64 bytes bf16 per row)
constexpr int NKT = D_IN / BK;        // 64 K-tiles
constexpr int TILES_H = H_OUT / TH;   // 32
constexpr int REGION  = 8192;         // per-expert list capacity
constexpr int BUFSZ   = TM * BK;      // shorts per LDS buffer (4096 = 8 KB)
constexpr int MAXTILES = N_TOK * 2 / TM + NEXP;   // 136 worst-case active tiles
constexpr int GRID_GEMM = MAXTILES * TILES_H;     // 4352 (divisible by 8)

typedef __attribute__((ext_vector_type(8))) short bf16x8;
typedef __attribute__((ext_vector_type(4))) float f32x4;

__device__ __forceinline__ short f2bf(float f) {
    unsigned u = __float_as_uint(f);
    u += 0x7FFF + ((u >> 16) & 1);   // RNE
    return (short)(u >> 16);
}

__device__ __forceinline__ void gload16(const void* g, void* l) {
    __builtin_amdgcn_global_load_lds(
        (const __attribute__((address_space(1))) unsigned int*)g,
        (__attribute__((address_space(3))) unsigned int*)l, 16, 0, 0);
}

// ---------------------------------------------------------------------------
// Kernel 1: gating (one wave per token, fuses x->bf16) + FUSED scatter +
// grid-stride expert_w -> bf16 repack into TILE-PANEL layout wb:
//   [e][th(32)][kt(64)][row(128)][k(32)]  (8 KB contiguous per B K-tile)
// ---------------------------------------------------------------------------
__global__ __launch_bounds__(256) void gate_cvt_kernel(
    const float* __restrict__ x, const float* __restrict__ gate_w,
    const float* __restrict__ gate_b, float* __restrict__ ent_partial,
    short* __restrict__ xb,
    const float* __restrict__ expert_w, short* __restrict__ wb,
    int* __restrict__ cursors, int* __restrict__ tok_list,
    float* __restrict__ w_list)
{
    __shared__ float ent_s[4];
    __shared__ int   lcnt[NEXP], lbase[NEXP];
    __shared__ int   pick_e[4][2], pick_p[4][2];
    __shared__ float pick_w[4][2];

    const int wv = threadIdx.x >> 6;
    const int lane = threadIdx.x & 63;
    const int t = blockIdx.x * 4 + wv;

    if (threadIdx.x < NEXP) lcnt[threadIdx.x] = 0;

    float acc[NEXP];
#pragma unroll
    for (int e = 0; e < NEXP; ++e) acc[e] = 0.f;

    const float4* xr = (const float4*)(x + (size_t)t * D_IN);
    short* xbr = xb + (size_t)t * D_IN;
#pragma unroll
    for (int i = 0; i < D_IN / 256; ++i) {           // 8 iters
        float4 xv = xr[lane + i * 64];
        short4 s4;
        s4.x = f2bf(xv.x); s4.y = f2bf(xv.y); s4.z = f2bf(xv.z); s4.w = f2bf(xv.w);
        *(short4*)(xbr + i * 256 + lane * 4) = s4;
#pragma unroll
        for (int e = 0; e < NEXP; ++e) {
            float4 gv = ((const float4*)(gate_w + e * D_IN))[lane + i * 64];
            acc[e] += xv.x * gv.x + xv.y * gv.y + xv.z * gv.z + xv.w * gv.w;
        }
    }
#pragma unroll
    for (int e = 0; e < NEXP; ++e)
#pragma unroll
        for (int m = 32; m >= 1; m >>= 1) acc[e] += __shfl_xor(acc[e], m, 64);

    __syncthreads();   // lcnt zeroed
    if (lane == 0) {
        float lg[NEXP], p[NEXP];
        float mx = -1e30f;
#pragma unroll
        for (int e = 0; e < NEXP; ++e) { lg[e] = acc[e] + gate_b[e]; mx = fmaxf(mx, lg[e]); }
        float s = 0.f;
#pragma unroll
        for (int e = 0; e < NEXP; ++e) { p[e] = expf(lg[e] - mx); s += p[e]; }
        float inv = 1.f / s;
        float ent = 0.f;
#pragma unroll
        for (int e = 0; e < NEXP; ++e) { p[e] *= inv; ent -= p[e] * logf(p[e] + 1e-10f); }
        int e1 = 0; float b1 = p[0];
#pragma unroll
        for (int e = 1; e < NEXP; ++e) if (p[e] > b1) { b1 = p[e]; e1 = e; }
        int e2 = (e1 == 0) ? 1 : 0; float b2 = p[e2];
#pragma unroll
        for (int e = 0; e < NEXP; ++e)
            if (e != e1 && e != ((e1 == 0) ? 1 : 0) && p[e] > b2) { b2 = p[e]; e2 = e; }
        int p0 = atomicAdd(&lcnt[e1], 1);
        int p1 = atomicAdd(&lcnt[e2], 1);
        pick_e[wv][0] = e1; pick_p[wv][0] = p0; pick_w[wv][0] = b1;
        pick_e[wv][1] = e2; pick_p[wv][1] = p1; pick_w[wv][1] = b2;
        ent_s[wv] = ent;
    }
    __syncthreads();
    if (threadIdx.x < NEXP)
        lbase[threadIdx.x] = lcnt[threadIdx.x] ?
            atomicAdd(&cursors[threadIdx.x], lcnt[threadIdx.x]) : 0;
    if (threadIdx.x == 0)
        ent_partial[blockIdx.x] = ent_s[0] + ent_s[1] + ent_s[2] + ent_s[3];
    __syncthreads();
    if (lane == 0) {
#pragma unroll
        for (int k = 0; k < 2; ++k) {
            int e = pick_e[wv][k];
            int dst = e * REGION + lbase[e] + pick_p[wv][k];
            tok_list[dst] = t;
            w_list[dst] = pick_w[wv][k];
        }
    }

    // ---- appended: expert_w fp32 -> bf16 tile-panel repack (grid-stride).
    const int total = NEXP << 20;                    // 8.39M chunks
    int stride = gridDim.x * 256;
    for (int d = blockIdx.x * 256 + threadIdx.x; d < total; d += stride) {
        int e    = d >> 20;
        int th   = (d >> 15) & 31;
        int kt   = (d >> 9) & 63;
        int row  = (d >> 2) & 127;
        int q    = d & 3;
        int h = th * 128 + row;
        int k = kt * 32 + q * 8;
        const float4* s = (const float4*)(expert_w + ((size_t)e * H_OUT + h) * D_IN + k);
        float4 a = s[0], b = s[1];
        bf16x8 v;
        v[0] = f2bf(a.x); v[1] = f2bf(a.y); v[2] = f2bf(a.z); v[3] = f2bf(a.w);
        v[4] = f2bf(b.x); v[5] = f2bf(b.y); v[6] = f2bf(b.z); v[7] = f2bf(b.w);
        *(bf16x8*)(wb + (size_t)d * 8) = v;
    }
}

// ---------------------------------------------------------------------------
// Kernel 2: finalize — entropy reduce + overuse penalty (after gemm).
// ---------------------------------------------------------------------------
__global__ __launch_bounds__(256) void finalize_kernel(
    const int* __restrict__ counts, const float* __restrict__ ent_partial,
    float* __restrict__ loss_out)
{
    __shared__ float red[256];
    float s = 0.f;
    for (int i = threadIdx.x; i < N_TOK / 4; i += 256) s += ent_partial[i];
    red[threadIdx.x] = s;
    __syncthreads();
    for (int st = 128; st > 0; st >>= 1) {
        if (threadIdx.x < st) red[threadIdx.x] += red[threadIdx.x + st];
        __syncthreads();
    }
    if (threadIdx.x == 0) {
        float loss = ENT_W * red[0] / (float)N_TOK;
        for (int e = 0; e < NEXP; ++e) {
            float r = (float)counts[e] / (float)N_TOK - MAX_USAGE;
            if (r > 0.f) loss += r;
        }
        loss_out[0] = loss;
    }
}

// ---------------------------------------------------------------------------
// Kernel 3: grouped GEMM — r16's 8-wave depth-2 counted pipeline, with
// fragment offsets collapsed to base+immediate (swizzle identity:
// (row>>1)&3 == (rr>>1)&3 since mi*16 / wr*64 don't touch row bits 1-2)
// and __launch_bounds__(512,8): 4 blocks/CU x 8 waves = 32 waves/CU.
// ---------------------------------------------------------------------------
__global__ __launch_bounds__(512, 8) void moe_gemm(
    const short* __restrict__ xb, const short* __restrict__ wb,
    const float* __restrict__ expert_b, const int* __restrict__ tok_list,
    const float* __restrict__ w_list, const int* __restrict__ cursors,
    float* __restrict__ out)
{
    const int bid = blockIdx.x;
    const int swz = (bid & 7) * (GRID_GEMM / 8) + (bid >> 3);
    const int tIdx = swz >> 5;
    const int th   = swz & 31;

    // inline plan: map tIdx -> (expert, tile) from cursors (8 scalar loads)
    int e = -1, base = 0, valid = 0;
    {
        int n = 0;
        for (int ee = 0; ee < NEXP; ++ee) {
            int cnt = cursors[ee];
            int nt = (cnt + TM - 1) / TM;
            if (tIdx < n + nt) {
                e = ee;
                int i = tIdx - n;
                base = ee * REGION + i * TM;
                valid = cnt - i * TM;
                if (valid > TM) valid = TM;
                break;
            }
            n += nt;
        }
    }
    if (e < 0) return;
    const int hbase = th * TH;

    __shared__ __align__(16) short A_s[2][BUFSZ];   // 2 x 8 KB
    __shared__ __align__(16) short B_s[2][BUFSZ];   // 2 x 8 KB
    __shared__ int   tok_s[TM];
    __shared__ float wgt_s[TM];

    const int tid = threadIdx.x;                    // 0..511
    if (tid < TM) {
        bool v = tid < valid;
        tok_s[tid] = v ? tok_list[base + tid] : tok_list[base];
        wgt_s[tid] = v ? w_list[base + tid] : 0.f;
    }
    __syncthreads();

    const int lane = tid & 63;
    const int wv = tid >> 6;                        // 0..7

    // staging: 8 x 1KB chunks per operand-tile; wave wv owns chunk wv.
    // chunk c covers rows c*16..c*16+15; lane l -> row c*16+(l>>2),
    // source slot s2=(l&3)^((l>>3)&3) (involution; (row>>1)&3 == (l>>3)&3).
    const char* asrc;
    const char* bsrc;
    const int dst_off = wv * 512;                   // shorts (+lane*16B by HW)
    {
        int r = wv * 16 + (lane >> 2);
        int s2 = (lane & 3) ^ ((lane >> 3) & 3);
        asrc = (const char*)(xb + (size_t)tok_s[r] * D_IN) + s2 * 16;
        const char* bpanel = (const char*)wb +
            ((size_t)(e * TILES_H + th)) * (64 * 8192);
        bsrc = bpanel + wv * 1024 + (lane >> 2) * 64 + s2 * 16;
    }

    const int rr = lane & 15, kg = lane >> 4;
    const int wr = wv >> 2;                         // 0..1  (64-row strip)
    const int wc = wv & 3;                          // 0..3  (32-col strip)

    // fragment bases (shorts); per-frag deltas are compile-time immediates
    // (mi*512 shorts = 16 rows; swizzle term depends only on rr bits 1-2).
    const int fswz = (kg ^ ((rr >> 1) & 3)) * 8;
    const int aoff0 = (wr * 64 + rr) * 32 + fswz;
    const int boff0 = (wc * 32 + rr) * 32 + fswz;

    f32x4 acc[4][2] = {};

#define STAGE_KT(buf)                                                      \
    {                                                                      \
        gload16(asrc, (short*)A_s[buf] + dst_off); asrc += BK * 2;         \
        gload16(bsrc, (short*)B_s[buf] + dst_off); bsrc += 8192;           \
    }

    // prologue: stage K-tiles 0 (buf0) and 1 (buf1); certify tile 0 only.
    STAGE_KT(0);
    STAGE_KT(1);
    asm volatile("s_waitcnt vmcnt(2)" ::: "memory");   // tile 0 landed
    __builtin_amdgcn_sched_barrier(0);
    __builtin_amdgcn_s_barrier();

    for (int kt = 0; kt < NKT; ++kt) {
        const short* Ac = A_s[kt & 1];
        const short* Bc = B_s[kt & 1];

        // consume current tile entirely into registers
        bf16x8 af[4], bv[2];
#pragma unroll
        for (int mi = 0; mi < 4; ++mi)
            af[mi] = *(const bf16x8*)&Ac[aoff0 + mi * 512];
#pragma unroll
        for (int ni = 0; ni < 2; ++ni)
            bv[ni] = *(const bf16x8*)&Bc[boff0 + ni * 512];
        asm volatile("s_waitcnt lgkmcnt(0)" ::: "memory");
        __builtin_amdgcn_sched_barrier(0);
        __builtin_amdgcn_s_barrier();          // all waves done reading buf[kt&1]

        // stage tile kt+2 into the freed buffer (loads fly under MFMA)
        if (kt + 2 < NKT) STAGE_KT(kt & 1);

        __builtin_amdgcn_s_setprio(1);
#pragma unroll
        for (int mi = 0; mi < 4; ++mi)
#pragma unroll
            for (int ni = 0; ni < 2; ++ni)
                acc[mi][ni] = __builtin_amdgcn_mfma_f32_16x16x32_bf16(
                    af[mi], bv[ni], acc[mi][ni], 0, 0, 0);
        __builtin_amdgcn_s_setprio(0);

        // certify tile kt+1 (issued one full tile ago); deep prefetch stays.
        if (kt + 2 < NKT) {
            asm volatile("s_waitcnt vmcnt(2)" ::: "memory");
        } else if (kt + 1 < NKT) {
            asm volatile("s_waitcnt vmcnt(0)" ::: "memory");
        }
        __builtin_amdgcn_sched_barrier(0);
        __builtin_amdgcn_s_barrier();          // buf[(kt+1)&1] valid for all
    }
#undef STAGE_KT

    // epilogue: C/D layout col=lane&15, row=(lane>>4)*4+i
    const float* bias = expert_b + (size_t)e * H_OUT + hbase;
    float be[2];
#pragma unroll
    for (int ni = 0; ni < 2; ++ni) be[ni] = bias[wc * 32 + ni * 16 + rr];
#pragma unroll
    for (int mi = 0; mi < 4; ++mi) {
#pragma unroll
        for (int i = 0; i < 4; ++i) {
            int r = wr * 64 + mi * 16 + kg * 4 + i;
            if (r < valid) {
                float w = wgt_s[r];
                float* orow = out + (size_t)tok_s[r] * H_OUT + hbase;
#pragma unroll
                for (int ni = 0; ni < 2; ++ni) {
                    int col = wc * 32 + ni * 16 + rr;
                    atomicAdd(orow + col, w * (acc[mi][ni][i] + be[ni]));
                }
            }
        }
    }
}

// ---------------------------------------------------------------------------
// Workspace layout (<= 162 MB, proven budget):
//   128K     cursors     64 B
//   132K     ent_partial 8 KB
//   160K     tok_list    256 KB  (8 regions x 8192)
//   416K     w_list      256 KB
//   1M       xb  bf16    32 MB
//   34M      wb  bf16    128 MB  (tile-panel layout)
// ---------------------------------------------------------------------------
extern "C" void kernel_launch(void* const* d_in, const int* in_sizes, int n_in,
                              void* d_out, int out_size, void* d_ws, size_t ws_size,
                              hipStream_t stream) {
    const float* x        = (const float*)d_in[0];
    const float* gate_w   = (const float*)d_in[1];
    const float* gate_b   = (const float*)d_in[2];
    const float* expert_w = (const float*)d_in[3];
    const float* expert_b = (const float*)d_in[4];
    float* out = (float*)d_out;
    char* ws = (char*)d_ws;

    int*   cursors     = (int*)(ws + (128 << 10));
    float* ent_partial = (float*)(ws + (132 << 10));
    int*   tok_list    = (int*)(ws + (160 << 10));
    float* w_list      = (float*)(ws + (416 << 10));
    short* xb          = (short*)(ws + (1ull << 20));
    short* wb          = (short*)(ws + (34ull << 20));

    hipMemsetAsync(cursors, 0, 64, stream);
    hipMemsetAsync(d_out, 0, (size_t)out_size * sizeof(float), stream);

    gate_cvt_kernel<<<N_TOK / 4, 256, 0, stream>>>(
        x, gate_w, gate_b, ent_partial, xb, expert_w, wb,
        cursors, tok_list, w_list);
    moe_gemm<<<GRID_GEMM, 512, 0, stream>>>(
        xb, wb, expert_b, tok_list, w_list, cursors, out);
    finalize_kernel<<<1, 256, 0, stream>>>(cursors, ent_partial,
                                           out + (size_t)N_TOK * H_OUT);
}

// Round 18
// 612.977 us; speedup vs baseline: 1.0558x; 1.0558x over previous
//
#include <hip/hip_runtime.h>

// Problem constants
constexpr int N_TOK = 8192;      // B*S
constexpr int D_IN  = 2048;
constexpr int H_OUT = 4096;
constexpr int NEXP  = 8;
constexpr float ENT_W = 0.1f;
constexpr float MAX_USAGE = 0.3f;

// GEMM tiling: 128x128 tile, BK=32, 8 waves (512 thr) of 64x32 wave-tiles.
// acc[4][2]=32 AGPR + frags ~24 -> ~80 unified regs -> 6 waves/SIMD ->
// 3 blocks/CU x 8 waves = 24 waves/CU. This is the measured optimum of the
// occupancy axis: 2 blocks x 4 waves = 508us (r14), 3x8 = 484us (r16),
// 4x8 = 518us (r17, FETCH +73% -> L2 thrash). Do not push to (512,8).
constexpr int TM = 128;
constexpr int TH = 128;
constexpr int BK = 32;                // K-step (64 bytes bf16 per row)
constexpr int NKT = D_IN / BK;        // 64 K-tiles
constexpr int TILES_H = H_OUT / TH;   // 32
constexpr int REGION  = 8192;         // per-expert list capacity
constexpr int BUFSZ   = TM * BK;      // shorts per LDS buffer (4096 = 8 KB)
constexpr int MAXTILES = N_TOK * 2 / TM + NEXP;   // 136 worst-case active tiles
constexpr int GRID_GEMM = MAXTILES * TILES_H;     // 4352 (divisible by 8)

typedef __attribute__((ext_vector_type(8))) short bf16x8;
typedef __attribute__((ext_vector_type(4))) float f32x4;

__device__ __forceinline__ short f2bf(float f) {
    unsigned u = __float_as_uint(f);
    u += 0x7FFF + ((u >> 16) & 1);   // RNE
    return (short)(u >> 16);
}

__device__ __forceinline__ void gload16(const void* g, void* l) {
    __builtin_amdgcn_global_load_lds(
        (const __attribute__((address_space(1))) unsigned int*)g,
        (__attribute__((address_space(3))) unsigned int*)l, 16, 0, 0);
}

// ---------------------------------------------------------------------------
// Kernel 1: gating (one wave per token, fuses x->bf16) + FUSED scatter +
// grid-stride expert_w -> bf16 repack into TILE-PANEL layout wb:
//   [e][th(32)][kt(64)][row(128)][k(32)]  (8 KB contiguous per B K-tile)
// ---------------------------------------------------------------------------
__global__ __launch_bounds__(256) void gate_cvt_kernel(
    const float* __restrict__ x, const float* __restrict__ gate_w,
    const float* __restrict__ gate_b, float* __restrict__ ent_partial,
    short* __restrict__ xb,
    const float* __restrict__ expert_w, short* __restrict__ wb,
    int* __restrict__ cursors, int* __restrict__ tok_list,
    float* __restrict__ w_list)
{
    __shared__ float ent_s[4];
    __shared__ int   lcnt[NEXP], lbase[NEXP];
    __shared__ int   pick_e[4][2], pick_p[4][2];
    __shared__ float pick_w[4][2];

    const int wv = threadIdx.x >> 6;
    const int lane = threadIdx.x & 63;
    const int t = blockIdx.x * 4 + wv;

    if (threadIdx.x < NEXP) lcnt[threadIdx.x] = 0;

    float acc[NEXP];
#pragma unroll
    for (int e = 0; e < NEXP; ++e) acc[e] = 0.f;

    const float4* xr = (const float4*)(x + (size_t)t * D_IN);
    short* xbr = xb + (size_t)t * D_IN;
#pragma unroll
    for (int i = 0; i < D_IN / 256; ++i) {           // 8 iters
        float4 xv = xr[lane + i * 64];
        short4 s4;
        s4.x = f2bf(xv.x); s4.y = f2bf(xv.y); s4.z = f2bf(xv.z); s4.w = f2bf(xv.w);
        *(short4*)(xbr + i * 256 + lane * 4) = s4;
#pragma unroll
        for (int e = 0; e < NEXP; ++e) {
            float4 gv = ((const float4*)(gate_w + e * D_IN))[lane + i * 64];
            acc[e] += xv.x * gv.x + xv.y * gv.y + xv.z * gv.z + xv.w * gv.w;
        }
    }
#pragma unroll
    for (int e = 0; e < NEXP; ++e)
#pragma unroll
        for (int m = 32; m >= 1; m >>= 1) acc[e] += __shfl_xor(acc[e], m, 64);

    __syncthreads();   // lcnt zeroed
    if (lane == 0) {
        float lg[NEXP], p[NEXP];
        float mx = -1e30f;
#pragma unroll
        for (int e = 0; e < NEXP; ++e) { lg[e] = acc[e] + gate_b[e]; mx = fmaxf(mx, lg[e]); }
        float s = 0.f;
#pragma unroll
        for (int e = 0; e < NEXP; ++e) { p[e] = expf(lg[e] - mx); s += p[e]; }
        float inv = 1.f / s;
        float ent = 0.f;
#pragma unroll
        for (int e = 0; e < NEXP; ++e) { p[e] *= inv; ent -= p[e] * logf(p[e] + 1e-10f); }
        int e1 = 0; float b1 = p[0];
#pragma unroll
        for (int e = 1; e < NEXP; ++e) if (p[e] > b1) { b1 = p[e]; e1 = e; }
        int e2 = (e1 == 0) ? 1 : 0; float b2 = p[e2];
#pragma unroll
        for (int e = 0; e < NEXP; ++e)
            if (e != e1 && e != ((e1 == 0) ? 1 : 0) && p[e] > b2) { b2 = p[e]; e2 = e; }
        int p0 = atomicAdd(&lcnt[e1], 1);
        int p1 = atomicAdd(&lcnt[e2], 1);
        pick_e[wv][0] = e1; pick_p[wv][0] = p0; pick_w[wv][0] = b1;
        pick_e[wv][1] = e2; pick_p[wv][1] = p1; pick_w[wv][1] = b2;
        ent_s[wv] = ent;
    }
    __syncthreads();
    if (threadIdx.x < NEXP)
        lbase[threadIdx.x] = lcnt[threadIdx.x] ?
            atomicAdd(&cursors[threadIdx.x], lcnt[threadIdx.x]) : 0;
    if (threadIdx.x == 0)
        ent_partial[blockIdx.x] = ent_s[0] + ent_s[1] + ent_s[2] + ent_s[3];
    __syncthreads();
    if (lane == 0) {
#pragma unroll
        for (int k = 0; k < 2; ++k) {
            int e = pick_e[wv][k];
            int dst = e * REGION + lbase[e] + pick_p[wv][k];
            tok_list[dst] = t;
            w_list[dst] = pick_w[wv][k];
        }
    }

    // ---- appended: expert_w fp32 -> bf16 tile-panel repack (grid-stride).
    const int total = NEXP << 20;                    // 8.39M chunks
    int stride = gridDim.x * 256;
    for (int d = blockIdx.x * 256 + threadIdx.x; d < total; d += stride) {
        int e    = d >> 20;
        int th   = (d >> 15) & 31;
        int kt   = (d >> 9) & 63;
        int row  = (d >> 2) & 127;
        int q    = d & 3;
        int h = th * 128 + row;
        int k = kt * 32 + q * 8;
        const float4* s = (const float4*)(expert_w + ((size_t)e * H_OUT + h) * D_IN + k);
        float4 a = s[0], b = s[1];
        bf16x8 v;
        v[0] = f2bf(a.x); v[1] = f2bf(a.y); v[2] = f2bf(a.z); v[3] = f2bf(a.w);
        v[4] = f2bf(b.x); v[5] = f2bf(b.y); v[6] = f2bf(b.z); v[7] = f2bf(b.w);
        *(bf16x8*)(wb + (size_t)d * 8) = v;
    }
}

// ---------------------------------------------------------------------------
// Kernel 2: finalize — entropy reduce + overuse penalty (after gemm).
// ---------------------------------------------------------------------------
__global__ __launch_bounds__(256) void finalize_kernel(
    const int* __restrict__ counts, const float* __restrict__ ent_partial,
    float* __restrict__ loss_out)
{
    __shared__ float red[256];
    float s = 0.f;
    for (int i = threadIdx.x; i < N_TOK / 4; i += 256) s += ent_partial[i];
    red[threadIdx.x] = s;
    __syncthreads();
    for (int st = 128; st > 0; st >>= 1) {
        if (threadIdx.x < st) red[threadIdx.x] += red[threadIdx.x + st];
        __syncthreads();
    }
    if (threadIdx.x == 0) {
        float loss = ENT_W * red[0] / (float)N_TOK;
        for (int e = 0; e < NEXP; ++e) {
            float r = (float)counts[e] / (float)N_TOK - MAX_USAGE;
            if (r > 0.f) loss += r;
        }
        loss_out[0] = loss;
    }
}

// ---------------------------------------------------------------------------
// Kernel 3: grouped GEMM — r16 configuration (best measured: 484 us,
// MfmaUtil 25.1, Occupancy 64%): 8-wave 64x32 wave-tiles, depth-2 counted
// vmcnt pipeline, 33 KB LDS, (512,6) -> 3 blocks/CU = 24 waves/CU.
// Inline plan from cursors; bijective XCD swizzle; tile-panel B staging;
// involution swizzle (0 bank conflicts measured).
// ---------------------------------------------------------------------------
__global__ __launch_bounds__(512, 6) void moe_gemm(
    const short* __restrict__ xb, const short* __restrict__ wb,
    const float* __restrict__ expert_b, const int* __restrict__ tok_list,
    const float* __restrict__ w_list, const int* __restrict__ cursors,
    float* __restrict__ out)
{
    const int bid = blockIdx.x;
    const int swz = (bid & 7) * (GRID_GEMM / 8) + (bid >> 3);
    const int tIdx = swz >> 5;
    const int th   = swz & 31;

    // inline plan: map tIdx -> (expert, tile) from cursors (8 scalar loads)
    int e = -1, base = 0, valid = 0;
    {
        int n = 0;
        for (int ee = 0; ee < NEXP; ++ee) {
            int cnt = cursors[ee];
            int nt = (cnt + TM - 1) / TM;
            if (tIdx < n + nt) {
                e = ee;
                int i = tIdx - n;
                base = ee * REGION + i * TM;
                valid = cnt - i * TM;
                if (valid > TM) valid = TM;
                break;
            }
            n += nt;
        }
    }
    if (e < 0) return;
    const int hbase = th * TH;

    __shared__ __align__(16) short A_s[2][BUFSZ];   // 2 x 8 KB
    __shared__ __align__(16) short B_s[2][BUFSZ];   // 2 x 8 KB
    __shared__ int   tok_s[TM];
    __shared__ float wgt_s[TM];

    const int tid = threadIdx.x;                    // 0..511
    if (tid < TM) {
        bool v = tid < valid;
        tok_s[tid] = v ? tok_list[base + tid] : tok_list[base];
        wgt_s[tid] = v ? w_list[base + tid] : 0.f;
    }
    __syncthreads();

    const int lane = tid & 63;
    const int wv = tid >> 6;                        // 0..7

    // staging: 8 x 1KB chunks per operand-tile; wave wv owns chunk wv.
    // chunk c covers rows c*16..c*16+15; lane l -> row c*16+(l>>2),
    // source slot s2=(l&3)^((l>>3)&3) (involution; (row>>1)&3 == (l>>3)&3).
    // A: gathered xb rows. B: tile-panel wb (8KB contiguous per K-tile).
    const char* asrc;
    const char* bsrc;
    const int dst_off = wv * 512;                   // shorts (+lane*16B by HW)
    {
        int r = wv * 16 + (lane >> 2);
        int s2 = (lane & 3) ^ ((lane >> 3) & 3);
        asrc = (const char*)(xb + (size_t)tok_s[r] * D_IN) + s2 * 16;
        const char* bpanel = (const char*)wb +
            ((size_t)(e * TILES_H + th)) * (64 * 8192);
        bsrc = bpanel + wv * 1024 + (lane >> 2) * 64 + s2 * 16;
    }

    const int rr = lane & 15, kg = lane >> 4;
    const int wr = wv >> 2;                         // 0..1  (64-row strip)
    const int wc = wv & 3;                          // 0..3  (32-col strip)

    // fragment LDS offsets (shorts), swizzled to match staging involution
    int aoff[4], boff[2];
#pragma unroll
    for (int mi = 0; mi < 4; ++mi) {
        int row = wr * 64 + mi * 16 + rr;
        aoff[mi] = row * 32 + (kg ^ ((row >> 1) & 3)) * 8;
    }
#pragma unroll
    for (int ni = 0; ni < 2; ++ni) {
        int rowb = wc * 32 + ni * 16 + rr;
        boff[ni] = rowb * 32 + (kg ^ ((rowb >> 1) & 3)) * 8;
    }

    f32x4 acc[4][2] = {};

#define STAGE_KT(buf)                                                      \
    {                                                                      \
        gload16(asrc, (short*)A_s[buf] + dst_off); asrc += BK * 2;         \
        gload16(bsrc, (short*)B_s[buf] + dst_off); bsrc += 8192;           \
    }

    // prologue: stage K-tiles 0 (buf0) and 1 (buf1); certify tile 0 only.
    STAGE_KT(0);
    STAGE_KT(1);
    asm volatile("s_waitcnt vmcnt(2)" ::: "memory");   // tile 0 landed
    __builtin_amdgcn_sched_barrier(0);
    __builtin_amdgcn_s_barrier();

    for (int kt = 0; kt < NKT; ++kt) {
        const short* Ac = A_s[kt & 1];
        const short* Bc = B_s[kt & 1];

        // consume current tile entirely into registers
        bf16x8 af[4], bv[2];
#pragma unroll
        for (int mi = 0; mi < 4; ++mi) af[mi] = *(const bf16x8*)&Ac[aoff[mi]];
#pragma unroll
        for (int ni = 0; ni < 2; ++ni) bv[ni] = *(const bf16x8*)&Bc[boff[ni]];
        asm volatile("s_waitcnt lgkmcnt(0)" ::: "memory");
        __builtin_amdgcn_sched_barrier(0);
        __builtin_amdgcn_s_barrier();          // all waves done reading buf[kt&1]

        // stage tile kt+2 into the freed buffer (loads fly under MFMA)
        if (kt + 2 < NKT) STAGE_KT(kt & 1);

        __builtin_amdgcn_s_setprio(1);
#pragma unroll
        for (int mi = 0; mi < 4; ++mi)
#pragma unroll
            for (int ni = 0; ni < 2; ++ni)
                acc[mi][ni] = __builtin_amdgcn_mfma_f32_16x16x32_bf16(
                    af[mi], bv[ni], acc[mi][ni], 0, 0, 0);
        __builtin_amdgcn_s_setprio(0);

        // certify tile kt+1 (issued one full tile ago); deep prefetch stays.
        if (kt + 2 < NKT) {
            asm volatile("s_waitcnt vmcnt(2)" ::: "memory");
        } else if (kt + 1 < NKT) {
            asm volatile("s_waitcnt vmcnt(0)" ::: "memory");
        }
        __builtin_amdgcn_sched_barrier(0);
        __builtin_amdgcn_s_barrier();          // buf[(kt+1)&1] valid for all
    }
#undef STAGE_KT

    // epilogue: C/D layout col=lane&15, row=(lane>>4)*4+i
    const float* bias = expert_b + (size_t)e * H_OUT + hbase;
    float be[2];
#pragma unroll
    for (int ni = 0; ni < 2; ++ni) be[ni] = bias[wc * 32 + ni * 16 + rr];
#pragma unroll
    for (int mi = 0; mi < 4; ++mi) {
#pragma unroll
        for (int i = 0; i < 4; ++i) {
            int r = wr * 64 + mi * 16 + kg * 4 + i;
            if (r < valid) {
                float w = wgt_s[r];
                float* orow = out + (size_t)tok_s[r] * H_OUT + hbase;
#pragma unroll
                for (int ni = 0; ni < 2; ++ni) {
                    int col = wc * 32 + ni * 16 + rr;
                    atomicAdd(orow + col, w * (acc[mi][ni][i] + be[ni]));
                }
            }
        }
    }
}

// ---------------------------------------------------------------------------
// Workspace layout (<= 162 MB, proven budget):
//   128K     cursors     64 B
//   132K     ent_partial 8 KB
//   160K     tok_list    256 KB  (8 regions x 8192)
//   416K     w_list      256 KB
//   1M       xb  bf16    32 MB
//   34M      wb  bf16    128 MB  (tile-panel layout)
// ---------------------------------------------------------------------------
extern "C" void kernel_launch(void* const* d_in, const int* in_sizes, int n_in,
                              void* d_out, int out_size, void* d_ws, size_t ws_size,
                              hipStream_t stream) {
    const float* x        = (const float*)d_in[0];
    const float* gate_w   = (const float*)d_in[1];
    const float* gate_b   = (const float*)d_in[2];
    const float* expert_w = (const float*)d_in[3];
    const float* expert_b = (const float*)d_in[4];
    float* out = (float*)d_out;
    char* ws = (char*)d_ws;

    int*   cursors     = (int*)(ws + (128 << 10));
    float* ent_partial = (float*)(ws + (132 << 10));
    int*   tok_list    = (int*)(ws + (160 << 10));
    float* w_list      = (float*)(ws + (416 << 10));
    short* xb          = (short*)(ws + (1ull << 20));
    short* wb          = (short*)(ws + (34ull << 20));

    hipMemsetAsync(cursors, 0, 64, stream);
    hipMemsetAsync(d_out, 0, (size_t)out_size * sizeof(float), stream);

    gate_cvt_kernel<<<N_TOK / 4, 256, 0, stream>>>(
        x, gate_w, gate_b, ent_partial, xb, expert_w, wb,
        cursors, tok_list, w_list);
    moe_gemm<<<GRID_GEMM, 512, 0, stream>>>(
        xb, wb, expert_b, tok_list, w_list, cursors, out);
    finalize_kernel<<<1, 256, 0, stream>>>(cursors, ent_partial,
                                           out + (size_t)N_TOK * H_OUT);
}